// Round 5
// baseline (863.297 us; speedup 1.0000x reference)
//
#include <hip/hip_runtime.h>
#include <stdint.h>

constexpr int NN = 20000;
constexpr int FF = 256;
constexpr int NODES_PER_BLOCK = 4;   // 512 threads = 4 nodes x 128 threads

typedef float v2f __attribute__((ext_vector_type(2)));

// Scalar path for CG coefficients: addrspace(4) (constant) + wave-uniform
// address -> s_load -> SGPR, splat into packed operand.
typedef const __attribute__((address_space(4))) float* cgp;
#define CGP(p) ((cgp)(uintptr_t)(p))

__device__ __forceinline__ v2f ld2(const float* p) {
    return *(const v2f*)p;
}
__device__ __forceinline__ void st2(float* p, v2f v) {
    *(v2f*)p = v;
}
__device__ __forceinline__ v2f pfma(v2f a, v2f b, v2f c) {
    return __builtin_elementwise_fma(a, b, c);
}
__device__ __forceinline__ v2f splat(float s) {
    v2f r = {s, s};
    return r;
}

__global__ __launch_bounds__(512, 8) void selfmix_kernel(
    const float* __restrict__ x0, const float* __restrict__ x1,
    const float* __restrict__ x2, const float* __restrict__ x3,
    const float* __restrict__ keep0, const float* __restrict__ keep1,
    const float* __restrict__ keep2, const float* __restrict__ keep3,
    const float* __restrict__ mix011, const float* __restrict__ cg011,
    const float* __restrict__ mix022, const float* __restrict__ cg022,
    const float* __restrict__ mix033, const float* __restrict__ cg033,
    const float* __restrict__ mix121, const float* __restrict__ cg121,
    const float* __restrict__ mix122, const float* __restrict__ cg122,
    const float* __restrict__ mix123, const float* __restrict__ cg123,
    const float* __restrict__ mix132, const float* __restrict__ cg132,
    const float* __restrict__ mix133, const float* __restrict__ cg133,
    const float* __restrict__ mix231, const float* __restrict__ cg231,
    const float* __restrict__ mix232, const float* __restrict__ cg232,
    const float* __restrict__ mix233, const float* __restrict__ cg233,
    float* __restrict__ out)
{
    const int sub = threadIdx.x >> 7;            // node sub-index in block
    const int fp  = threadIdx.x & 127;           // feature-pair index 0..127
    const int n   = blockIdx.x * NODES_PER_BLOCK + sub;
    const int f2  = fp * 2;

    // ---- per-feature coefficients (coalesced float2 loads) ----
    const v2f k0 = ld2(keep0 + f2), k1 = ld2(keep1 + f2);
    const v2f k2 = ld2(keep2 + f2), k3 = ld2(keep3 + f2);
    const v2f m011 = ld2(mix011 + f2), m022 = ld2(mix022 + f2), m033 = ld2(mix033 + f2);
    const v2f m121 = ld2(mix121 + f2), m122 = ld2(mix122 + f2), m123 = ld2(mix123 + f2);
    const v2f m132 = ld2(mix132 + f2), m133 = ld2(mix133 + f2);
    const v2f m231 = ld2(mix231 + f2), m232 = ld2(mix232 + f2), m233 = ld2(mix233 + f2);

    // ---- load x fragments (8 B/lane, fully coalesced) ----
    v2f a0 = ld2(x0 + n * FF + f2);
    v2f a1[3], a2[5], a3[7];
#pragma unroll
    for (int i = 0; i < 3; ++i) a1[i] = ld2(x1 + (n * 3 + i) * FF + f2);
#pragma unroll
    for (int i = 0; i < 5; ++i) a2[i] = ld2(x2 + (n * 5 + i) * FF + f2);
#pragma unroll
    for (int i = 0; i < 7; ++i) a3[i] = ld2(x3 + (n * 7 + i) * FF + f2);

    // ---- keep path ----
    v2f y0 = k0 * a0;
    v2f y1[3], y2[5], y3[7];
#pragma unroll
    for (int i = 0; i < 3; ++i) y1[i] = k1 * a1[i];
#pragma unroll
    for (int i = 0; i < 5; ++i) y2[i] = k2 * a2[i];
#pragma unroll
    for (int i = 0; i < 7; ++i) y3[i] = k3 * a3[i];

    // ---- mixing path: ij-outer, k-inner; packed FMAs, cg via SGPR splat ----

    // group (0,1) -> L=1
    {
        cgp cg = CGP(cg011);
        v2f t[3] = {};
#pragma unroll
        for (int j = 0; j < 3; ++j) {
            const v2f p = a0 * a1[j];
#pragma unroll
            for (int k = 0; k < 3; ++k) t[k] = pfma(splat(cg[j * 3 + k]), p, t[k]);
        }
#pragma unroll
        for (int k = 0; k < 3; ++k) y1[k] = pfma(m011, t[k], y1[k]);
    }

    // group (0,2) -> L=2
    {
        cgp cg = CGP(cg022);
        v2f t[5] = {};
#pragma unroll
        for (int j = 0; j < 5; ++j) {
            const v2f p = a0 * a2[j];
#pragma unroll
            for (int k = 0; k < 5; ++k) t[k] = pfma(splat(cg[j * 5 + k]), p, t[k]);
        }
#pragma unroll
        for (int k = 0; k < 5; ++k) y2[k] = pfma(m022, t[k], y2[k]);
    }

    // group (0,3) -> L=3
    {
        cgp cg = CGP(cg033);
        v2f t[7] = {};
#pragma unroll
        for (int j = 0; j < 7; ++j) {
            const v2f p = a0 * a3[j];
#pragma unroll
            for (int k = 0; k < 7; ++k) t[k] = pfma(splat(cg[j * 7 + k]), p, t[k]);
        }
#pragma unroll
        for (int k = 0; k < 7; ++k) y3[k] = pfma(m033, t[k], y3[k]);
    }

    // group (1,2) -> L=1,2,3 (shared products)
    {
        cgp c1 = CGP(cg121);
        cgp c2 = CGP(cg122);
        cgp c3 = CGP(cg123);
        v2f t1[3] = {}, t2[5] = {}, t3[7] = {};
#pragma unroll
        for (int i = 0; i < 3; ++i) {
#pragma unroll
            for (int j = 0; j < 5; ++j) {
                const int ij = i * 5 + j;
                const v2f p = a1[i] * a2[j];
#pragma unroll
                for (int k = 0; k < 3; ++k) t1[k] = pfma(splat(c1[ij * 3 + k]), p, t1[k]);
#pragma unroll
                for (int k = 0; k < 5; ++k) t2[k] = pfma(splat(c2[ij * 5 + k]), p, t2[k]);
#pragma unroll
                for (int k = 0; k < 7; ++k) t3[k] = pfma(splat(c3[ij * 7 + k]), p, t3[k]);
            }
        }
#pragma unroll
        for (int k = 0; k < 3; ++k) y1[k] = pfma(m121, t1[k], y1[k]);
#pragma unroll
        for (int k = 0; k < 5; ++k) y2[k] = pfma(m122, t2[k], y2[k]);
#pragma unroll
        for (int k = 0; k < 7; ++k) y3[k] = pfma(m123, t3[k], y3[k]);
    }

    // group (1,3) -> L=2,3 (shared products)
    {
        cgp c2 = CGP(cg132);
        cgp c3 = CGP(cg133);
        v2f t2[5] = {}, t3[7] = {};
#pragma unroll
        for (int i = 0; i < 3; ++i) {
#pragma unroll
            for (int j = 0; j < 7; ++j) {
                const int ij = i * 7 + j;
                const v2f p = a1[i] * a3[j];
#pragma unroll
                for (int k = 0; k < 5; ++k) t2[k] = pfma(splat(c2[ij * 5 + k]), p, t2[k]);
#pragma unroll
                for (int k = 0; k < 7; ++k) t3[k] = pfma(splat(c3[ij * 7 + k]), p, t3[k]);
            }
        }
#pragma unroll
        for (int k = 0; k < 5; ++k) y2[k] = pfma(m132, t2[k], y2[k]);
#pragma unroll
        for (int k = 0; k < 7; ++k) y3[k] = pfma(m133, t3[k], y3[k]);
    }

    // group (2,3) -> L=1,2,3 (shared products)
    {
        cgp c1 = CGP(cg231);
        cgp c2 = CGP(cg232);
        cgp c3 = CGP(cg233);
        v2f t1[3] = {}, t2[5] = {}, t3[7] = {};
#pragma unroll
        for (int i = 0; i < 5; ++i) {
#pragma unroll
            for (int j = 0; j < 7; ++j) {
                const int ij = i * 7 + j;
                const v2f p = a2[i] * a3[j];
#pragma unroll
                for (int k = 0; k < 3; ++k) t1[k] = pfma(splat(c1[ij * 3 + k]), p, t1[k]);
#pragma unroll
                for (int k = 0; k < 5; ++k) t2[k] = pfma(splat(c2[ij * 5 + k]), p, t2[k]);
#pragma unroll
                for (int k = 0; k < 7; ++k) t3[k] = pfma(splat(c3[ij * 7 + k]), p, t3[k]);
            }
        }
#pragma unroll
        for (int k = 0; k < 3; ++k) y1[k] = pfma(m231, t1[k], y1[k]);
#pragma unroll
        for (int k = 0; k < 5; ++k) y2[k] = pfma(m232, t2[k], y2[k]);
#pragma unroll
        for (int k = 0; k < 7; ++k) y3[k] = pfma(m233, t3[k], y3[k]);
    }

    // ---- store (concatenated outputs: y0 | y1 | y2 | y3) ----
    float* o0 = out;                          // N*1*F
    float* o1 = out + (size_t)NN * FF;        // N*3*F
    float* o2 = out + (size_t)NN * 4 * FF;    // N*5*F
    float* o3 = out + (size_t)NN * 9 * FF;    // N*7*F

    st2(o0 + n * FF + f2, y0);
#pragma unroll
    for (int k = 0; k < 3; ++k) st2(o1 + (n * 3 + k) * FF + f2, y1[k]);
#pragma unroll
    for (int k = 0; k < 5; ++k) st2(o2 + (n * 5 + k) * FF + f2, y2[k]);
#pragma unroll
    for (int k = 0; k < 7; ++k) st2(o3 + (n * 7 + k) * FF + f2, y3[k]);
}

extern "C" void kernel_launch(void* const* d_in, const int* in_sizes, int n_in,
                              void* d_out, int out_size, void* d_ws, size_t ws_size,
                              hipStream_t stream) {
    const float* x0 = (const float*)d_in[0];
    const float* x1 = (const float*)d_in[1];
    const float* x2 = (const float*)d_in[2];
    const float* x3 = (const float*)d_in[3];
    const float* keep0 = (const float*)d_in[4];
    const float* keep1 = (const float*)d_in[5];
    const float* keep2 = (const float*)d_in[6];
    const float* keep3 = (const float*)d_in[7];
    const float* mix011 = (const float*)d_in[8];
    const float* cg011  = (const float*)d_in[9];
    const float* mix022 = (const float*)d_in[10];
    const float* cg022  = (const float*)d_in[11];
    const float* mix033 = (const float*)d_in[12];
    const float* cg033  = (const float*)d_in[13];
    const float* mix121 = (const float*)d_in[14];
    const float* cg121  = (const float*)d_in[15];
    const float* mix122 = (const float*)d_in[16];
    const float* cg122  = (const float*)d_in[17];
    const float* mix123 = (const float*)d_in[18];
    const float* cg123  = (const float*)d_in[19];
    const float* mix132 = (const float*)d_in[20];
    const float* cg132  = (const float*)d_in[21];
    const float* mix133 = (const float*)d_in[22];
    const float* cg133  = (const float*)d_in[23];
    const float* mix231 = (const float*)d_in[24];
    const float* cg231  = (const float*)d_in[25];
    const float* mix232 = (const float*)d_in[26];
    const float* cg232  = (const float*)d_in[27];
    const float* mix233 = (const float*)d_in[28];
    const float* cg233  = (const float*)d_in[29];

    dim3 grid(NN / NODES_PER_BLOCK);  // 5000
    dim3 block(512);                  // 8 waves = 4 nodes (128 threads each)
    hipLaunchKernelGGL(selfmix_kernel, grid, block, 0, stream,
                       x0, x1, x2, x3,
                       keep0, keep1, keep2, keep3,
                       mix011, cg011, mix022, cg022, mix033, cg033,
                       mix121, cg121, mix122, cg122, mix123, cg123,
                       mix132, cg132, mix133, cg133,
                       mix231, cg231, mix232, cg232, mix233, cg233,
                       (float*)d_out);
}

// Round 6
// 591.972 us; speedup vs baseline: 1.4583x; 1.4583x over previous
//
#include <hip/hip_runtime.h>
#include <stdint.h>

constexpr int NN = 20000;
constexpr int FF = 256;
constexpr int NODES_PER_BLOCK = 2;   // 256 threads = 2 nodes x 128 threads (4 waves)

typedef float v2f __attribute__((ext_vector_type(2)));

// Scalar path for CG coefficients: addrspace(4) (constant) + wave-uniform
// address -> s_load -> SGPR, splat into packed operand.
typedef const __attribute__((address_space(4))) float* cgp;
#define CGP(p) ((cgp)(uintptr_t)(p))

__device__ __forceinline__ v2f ld2(const float* p) {
    return *(const v2f*)p;
}
__device__ __forceinline__ void st2(float* p, v2f v) {
    *(v2f*)p = v;
}
__device__ __forceinline__ v2f pfma(v2f a, v2f b, v2f c) {
    return __builtin_elementwise_fma(a, b, c);
}
__device__ __forceinline__ v2f splat(float s) {
    v2f r = {s, s};
    return r;
}

__global__ __launch_bounds__(256, 6) void selfmix_kernel(
    const float* __restrict__ x0, const float* __restrict__ x1,
    const float* __restrict__ x2, const float* __restrict__ x3,
    const float* __restrict__ keep0, const float* __restrict__ keep1,
    const float* __restrict__ keep2, const float* __restrict__ keep3,
    const float* __restrict__ mix011, const float* __restrict__ cg011,
    const float* __restrict__ mix022, const float* __restrict__ cg022,
    const float* __restrict__ mix033, const float* __restrict__ cg033,
    const float* __restrict__ mix121, const float* __restrict__ cg121,
    const float* __restrict__ mix122, const float* __restrict__ cg122,
    const float* __restrict__ mix123, const float* __restrict__ cg123,
    const float* __restrict__ mix132, const float* __restrict__ cg132,
    const float* __restrict__ mix133, const float* __restrict__ cg133,
    const float* __restrict__ mix231, const float* __restrict__ cg231,
    const float* __restrict__ mix232, const float* __restrict__ cg232,
    const float* __restrict__ mix233, const float* __restrict__ cg233,
    float* __restrict__ out)
{
    const int sub = threadIdx.x >> 7;            // node sub-index in block (0..1)
    const int fp  = threadIdx.x & 127;           // feature-pair index 0..127
    const int n   = blockIdx.x * NODES_PER_BLOCK + sub;
    const int f2  = fp * 2;

    // ---- per-feature coefficients (coalesced float2 loads) ----
    const v2f k0 = ld2(keep0 + f2), k1 = ld2(keep1 + f2);
    const v2f k2 = ld2(keep2 + f2), k3 = ld2(keep3 + f2);
    const v2f m011 = ld2(mix011 + f2), m022 = ld2(mix022 + f2), m033 = ld2(mix033 + f2);
    const v2f m121 = ld2(mix121 + f2), m122 = ld2(mix122 + f2), m123 = ld2(mix123 + f2);
    const v2f m132 = ld2(mix132 + f2), m133 = ld2(mix133 + f2);
    const v2f m231 = ld2(mix231 + f2), m232 = ld2(mix232 + f2), m233 = ld2(mix233 + f2);

    // ---- load x fragments (8 B/lane, fully coalesced) ----
    v2f a0 = ld2(x0 + n * FF + f2);
    v2f a1[3], a2[5], a3[7];
#pragma unroll
    for (int i = 0; i < 3; ++i) a1[i] = ld2(x1 + (n * 3 + i) * FF + f2);
#pragma unroll
    for (int i = 0; i < 5; ++i) a2[i] = ld2(x2 + (n * 5 + i) * FF + f2);
#pragma unroll
    for (int i = 0; i < 7; ++i) a3[i] = ld2(x3 + (n * 7 + i) * FF + f2);

    // ---- keep path ----
    v2f y0 = k0 * a0;
    v2f y1[3], y2[5], y3[7];
#pragma unroll
    for (int i = 0; i < 3; ++i) y1[i] = k1 * a1[i];
#pragma unroll
    for (int i = 0; i < 5; ++i) y2[i] = k2 * a2[i];
#pragma unroll
    for (int i = 0; i < 7; ++i) y3[i] = k3 * a3[i];

    // ---- mixing path: ij-outer, k-inner; packed FMAs, cg via SGPR splat ----

    // group (0,1) -> L=1
    {
        cgp cg = CGP(cg011);
        v2f t[3] = {};
#pragma unroll
        for (int j = 0; j < 3; ++j) {
            const v2f p = a0 * a1[j];
#pragma unroll
            for (int k = 0; k < 3; ++k) t[k] = pfma(splat(cg[j * 3 + k]), p, t[k]);
        }
#pragma unroll
        for (int k = 0; k < 3; ++k) y1[k] = pfma(m011, t[k], y1[k]);
    }

    // group (0,2) -> L=2
    {
        cgp cg = CGP(cg022);
        v2f t[5] = {};
#pragma unroll
        for (int j = 0; j < 5; ++j) {
            const v2f p = a0 * a2[j];
#pragma unroll
            for (int k = 0; k < 5; ++k) t[k] = pfma(splat(cg[j * 5 + k]), p, t[k]);
        }
#pragma unroll
        for (int k = 0; k < 5; ++k) y2[k] = pfma(m022, t[k], y2[k]);
    }

    // group (0,3) -> L=3
    {
        cgp cg = CGP(cg033);
        v2f t[7] = {};
#pragma unroll
        for (int j = 0; j < 7; ++j) {
            const v2f p = a0 * a3[j];
#pragma unroll
            for (int k = 0; k < 7; ++k) t[k] = pfma(splat(cg[j * 7 + k]), p, t[k]);
        }
#pragma unroll
        for (int k = 0; k < 7; ++k) y3[k] = pfma(m033, t[k], y3[k]);
    }

    // group (1,2) -> L=1,2,3 (shared products)
    {
        cgp c1 = CGP(cg121);
        cgp c2 = CGP(cg122);
        cgp c3 = CGP(cg123);
        v2f t1[3] = {}, t2[5] = {}, t3[7] = {};
#pragma unroll
        for (int i = 0; i < 3; ++i) {
#pragma unroll
            for (int j = 0; j < 5; ++j) {
                const int ij = i * 5 + j;
                const v2f p = a1[i] * a2[j];
#pragma unroll
                for (int k = 0; k < 3; ++k) t1[k] = pfma(splat(c1[ij * 3 + k]), p, t1[k]);
#pragma unroll
                for (int k = 0; k < 5; ++k) t2[k] = pfma(splat(c2[ij * 5 + k]), p, t2[k]);
#pragma unroll
                for (int k = 0; k < 7; ++k) t3[k] = pfma(splat(c3[ij * 7 + k]), p, t3[k]);
            }
        }
#pragma unroll
        for (int k = 0; k < 3; ++k) y1[k] = pfma(m121, t1[k], y1[k]);
#pragma unroll
        for (int k = 0; k < 5; ++k) y2[k] = pfma(m122, t2[k], y2[k]);
#pragma unroll
        for (int k = 0; k < 7; ++k) y3[k] = pfma(m123, t3[k], y3[k]);
    }

    // group (1,3) -> L=2,3 (shared products)
    {
        cgp c2 = CGP(cg132);
        cgp c3 = CGP(cg133);
        v2f t2[5] = {}, t3[7] = {};
#pragma unroll
        for (int i = 0; i < 3; ++i) {
#pragma unroll
            for (int j = 0; j < 7; ++j) {
                const int ij = i * 7 + j;
                const v2f p = a1[i] * a3[j];
#pragma unroll
                for (int k = 0; k < 5; ++k) t2[k] = pfma(splat(c2[ij * 5 + k]), p, t2[k]);
#pragma unroll
                for (int k = 0; k < 7; ++k) t3[k] = pfma(splat(c3[ij * 7 + k]), p, t3[k]);
            }
        }
#pragma unroll
        for (int k = 0; k < 5; ++k) y2[k] = pfma(m132, t2[k], y2[k]);
#pragma unroll
        for (int k = 0; k < 7; ++k) y3[k] = pfma(m133, t3[k], y3[k]);
    }

    // group (2,3) -> L=1,2,3 (shared products)
    {
        cgp c1 = CGP(cg231);
        cgp c2 = CGP(cg232);
        cgp c3 = CGP(cg233);
        v2f t1[3] = {}, t2[5] = {}, t3[7] = {};
#pragma unroll
        for (int i = 0; i < 5; ++i) {
#pragma unroll
            for (int j = 0; j < 7; ++j) {
                const int ij = i * 7 + j;
                const v2f p = a2[i] * a3[j];
#pragma unroll
                for (int k = 0; k < 3; ++k) t1[k] = pfma(splat(c1[ij * 3 + k]), p, t1[k]);
#pragma unroll
                for (int k = 0; k < 5; ++k) t2[k] = pfma(splat(c2[ij * 5 + k]), p, t2[k]);
#pragma unroll
                for (int k = 0; k < 7; ++k) t3[k] = pfma(splat(c3[ij * 7 + k]), p, t3[k]);
            }
        }
#pragma unroll
        for (int k = 0; k < 3; ++k) y1[k] = pfma(m231, t1[k], y1[k]);
#pragma unroll
        for (int k = 0; k < 5; ++k) y2[k] = pfma(m232, t2[k], y2[k]);
#pragma unroll
        for (int k = 0; k < 7; ++k) y3[k] = pfma(m233, t3[k], y3[k]);
    }

    // ---- store (concatenated outputs: y0 | y1 | y2 | y3) ----
    float* o0 = out;                          // N*1*F
    float* o1 = out + (size_t)NN * FF;        // N*3*F
    float* o2 = out + (size_t)NN * 4 * FF;    // N*5*F
    float* o3 = out + (size_t)NN * 9 * FF;    // N*7*F

    st2(o0 + n * FF + f2, y0);
#pragma unroll
    for (int k = 0; k < 3; ++k) st2(o1 + (n * 3 + k) * FF + f2, y1[k]);
#pragma unroll
    for (int k = 0; k < 5; ++k) st2(o2 + (n * 5 + k) * FF + f2, y2[k]);
#pragma unroll
    for (int k = 0; k < 7; ++k) st2(o3 + (n * 7 + k) * FF + f2, y3[k]);
}

extern "C" void kernel_launch(void* const* d_in, const int* in_sizes, int n_in,
                              void* d_out, int out_size, void* d_ws, size_t ws_size,
                              hipStream_t stream) {
    const float* x0 = (const float*)d_in[0];
    const float* x1 = (const float*)d_in[1];
    const float* x2 = (const float*)d_in[2];
    const float* x3 = (const float*)d_in[3];
    const float* keep0 = (const float*)d_in[4];
    const float* keep1 = (const float*)d_in[5];
    const float* keep2 = (const float*)d_in[6];
    const float* keep3 = (const float*)d_in[7];
    const float* mix011 = (const float*)d_in[8];
    const float* cg011  = (const float*)d_in[9];
    const float* mix022 = (const float*)d_in[10];
    const float* cg022  = (const float*)d_in[11];
    const float* mix033 = (const float*)d_in[12];
    const float* cg033  = (const float*)d_in[13];
    const float* mix121 = (const float*)d_in[14];
    const float* cg121  = (const float*)d_in[15];
    const float* mix122 = (const float*)d_in[16];
    const float* cg122  = (const float*)d_in[17];
    const float* mix123 = (const float*)d_in[18];
    const float* cg123  = (const float*)d_in[19];
    const float* mix132 = (const float*)d_in[20];
    const float* cg132  = (const float*)d_in[21];
    const float* mix133 = (const float*)d_in[22];
    const float* cg133  = (const float*)d_in[23];
    const float* mix231 = (const float*)d_in[24];
    const float* cg231  = (const float*)d_in[25];
    const float* mix232 = (const float*)d_in[26];
    const float* cg232  = (const float*)d_in[27];
    const float* mix233 = (const float*)d_in[28];
    const float* cg233  = (const float*)d_in[29];

    dim3 grid(NN / NODES_PER_BLOCK);  // 10000
    dim3 block(256);                  // 4 waves = 2 nodes (128 threads each)
    hipLaunchKernelGGL(selfmix_kernel, grid, block, 0, stream,
                       x0, x1, x2, x3,
                       keep0, keep1, keep2, keep3,
                       mix011, cg011, mix022, cg022, mix033, cg033,
                       mix121, cg121, mix122, cg122, mix123, cg123,
                       mix132, cg132, mix133, cg133,
                       mix231, cg231, mix232, cg232, mix233, cg233,
                       (float*)d_out);
}

// Round 7
// 194.002 us; speedup vs baseline: 4.4499x; 3.0514x over previous
//
#include <hip/hip_runtime.h>
#include <stdint.h>

constexpr int NN = 20000;
constexpr int FF = 256;
constexpr int NODES_PER_BLOCK = 4;   // 512 threads = 4 nodes x 128 threads (8 waves)

typedef float v2f __attribute__((ext_vector_type(2)));

// Scalar path for CG coefficients: addrspace(4) (constant) + wave-uniform
// address -> s_load -> SGPR, splat into packed operand.
typedef const __attribute__((address_space(4))) float* cgp;
#define CGP(p) ((cgp)(uintptr_t)(p))

__device__ __forceinline__ v2f ld2(const float* p) {
    return *(const v2f*)p;
}
__device__ __forceinline__ void st2(float* p, v2f v) {
    *(v2f*)p = v;
}
__device__ __forceinline__ v2f pfma(v2f a, v2f b, v2f c) {
    return __builtin_elementwise_fma(a, b, c);
}
__device__ __forceinline__ v2f splat(float s) {
    v2f r = {s, s};
    return r;
}

__global__ __launch_bounds__(512) void selfmix_kernel(
    const float* __restrict__ x0, const float* __restrict__ x1,
    const float* __restrict__ x2, const float* __restrict__ x3,
    const float* __restrict__ keep0, const float* __restrict__ keep1,
    const float* __restrict__ keep2, const float* __restrict__ keep3,
    const float* __restrict__ mix011, const float* __restrict__ cg011,
    const float* __restrict__ mix022, const float* __restrict__ cg022,
    const float* __restrict__ mix033, const float* __restrict__ cg033,
    const float* __restrict__ mix121, const float* __restrict__ cg121,
    const float* __restrict__ mix122, const float* __restrict__ cg122,
    const float* __restrict__ mix123, const float* __restrict__ cg123,
    const float* __restrict__ mix132, const float* __restrict__ cg132,
    const float* __restrict__ mix133, const float* __restrict__ cg133,
    const float* __restrict__ mix231, const float* __restrict__ cg231,
    const float* __restrict__ mix232, const float* __restrict__ cg232,
    const float* __restrict__ mix233, const float* __restrict__ cg233,
    float* __restrict__ out)
{
    const int sub = threadIdx.x >> 7;            // node sub-index in block (0..3)
    const int fp  = threadIdx.x & 127;           // feature-pair index 0..127
    const int n   = blockIdx.x * NODES_PER_BLOCK + sub;
    const int f2  = fp * 2;

    // ---- per-feature coefficients (coalesced float2 loads) ----
    const v2f k0 = ld2(keep0 + f2), k1 = ld2(keep1 + f2);
    const v2f k2 = ld2(keep2 + f2), k3 = ld2(keep3 + f2);
    const v2f m011 = ld2(mix011 + f2), m022 = ld2(mix022 + f2), m033 = ld2(mix033 + f2);
    const v2f m121 = ld2(mix121 + f2), m122 = ld2(mix122 + f2), m123 = ld2(mix123 + f2);
    const v2f m132 = ld2(mix132 + f2), m133 = ld2(mix133 + f2);
    const v2f m231 = ld2(mix231 + f2), m232 = ld2(mix232 + f2), m233 = ld2(mix233 + f2);

    // ---- load x fragments (8 B/lane, fully coalesced) ----
    v2f a0 = ld2(x0 + n * FF + f2);
    v2f a1[3], a2[5], a3[7];
#pragma unroll
    for (int i = 0; i < 3; ++i) a1[i] = ld2(x1 + (n * 3 + i) * FF + f2);
#pragma unroll
    for (int i = 0; i < 5; ++i) a2[i] = ld2(x2 + (n * 5 + i) * FF + f2);
#pragma unroll
    for (int i = 0; i < 7; ++i) a3[i] = ld2(x3 + (n * 7 + i) * FF + f2);

    // ---- keep path ----
    v2f y0 = k0 * a0;
    v2f y1[3], y2[5], y3[7];
#pragma unroll
    for (int i = 0; i < 3; ++i) y1[i] = k1 * a1[i];
#pragma unroll
    for (int i = 0; i < 5; ++i) y2[i] = k2 * a2[i];
#pragma unroll
    for (int i = 0; i < 7; ++i) y3[i] = k3 * a3[i];

    // ---- mixing path: ij-outer, k-inner; packed FMAs, cg via SGPR splat ----

    // group (0,1) -> L=1
    {
        cgp cg = CGP(cg011);
        v2f t[3] = {};
#pragma unroll
        for (int j = 0; j < 3; ++j) {
            const v2f p = a0 * a1[j];
#pragma unroll
            for (int k = 0; k < 3; ++k) t[k] = pfma(splat(cg[j * 3 + k]), p, t[k]);
        }
#pragma unroll
        for (int k = 0; k < 3; ++k) y1[k] = pfma(m011, t[k], y1[k]);
    }

    // group (0,2) -> L=2
    {
        cgp cg = CGP(cg022);
        v2f t[5] = {};
#pragma unroll
        for (int j = 0; j < 5; ++j) {
            const v2f p = a0 * a2[j];
#pragma unroll
            for (int k = 0; k < 5; ++k) t[k] = pfma(splat(cg[j * 5 + k]), p, t[k]);
        }
#pragma unroll
        for (int k = 0; k < 5; ++k) y2[k] = pfma(m022, t[k], y2[k]);
    }

    // group (0,3) -> L=3
    {
        cgp cg = CGP(cg033);
        v2f t[7] = {};
#pragma unroll
        for (int j = 0; j < 7; ++j) {
            const v2f p = a0 * a3[j];
#pragma unroll
            for (int k = 0; k < 7; ++k) t[k] = pfma(splat(cg[j * 7 + k]), p, t[k]);
        }
#pragma unroll
        for (int k = 0; k < 7; ++k) y3[k] = pfma(m033, t[k], y3[k]);
    }

    // group (1,2) -> L=1,2,3 (shared products)
    {
        cgp c1 = CGP(cg121);
        cgp c2 = CGP(cg122);
        cgp c3 = CGP(cg123);
        v2f t1[3] = {}, t2[5] = {}, t3[7] = {};
#pragma unroll
        for (int i = 0; i < 3; ++i) {
#pragma unroll
            for (int j = 0; j < 5; ++j) {
                const int ij = i * 5 + j;
                const v2f p = a1[i] * a2[j];
#pragma unroll
                for (int k = 0; k < 3; ++k) t1[k] = pfma(splat(c1[ij * 3 + k]), p, t1[k]);
#pragma unroll
                for (int k = 0; k < 5; ++k) t2[k] = pfma(splat(c2[ij * 5 + k]), p, t2[k]);
#pragma unroll
                for (int k = 0; k < 7; ++k) t3[k] = pfma(splat(c3[ij * 7 + k]), p, t3[k]);
            }
        }
#pragma unroll
        for (int k = 0; k < 3; ++k) y1[k] = pfma(m121, t1[k], y1[k]);
#pragma unroll
        for (int k = 0; k < 5; ++k) y2[k] = pfma(m122, t2[k], y2[k]);
#pragma unroll
        for (int k = 0; k < 7; ++k) y3[k] = pfma(m123, t3[k], y3[k]);
    }

    // group (1,3) -> L=2,3 (shared products)
    {
        cgp c2 = CGP(cg132);
        cgp c3 = CGP(cg133);
        v2f t2[5] = {}, t3[7] = {};
#pragma unroll
        for (int i = 0; i < 3; ++i) {
#pragma unroll
            for (int j = 0; j < 7; ++j) {
                const int ij = i * 7 + j;
                const v2f p = a1[i] * a3[j];
#pragma unroll
                for (int k = 0; k < 5; ++k) t2[k] = pfma(splat(c2[ij * 5 + k]), p, t2[k]);
#pragma unroll
                for (int k = 0; k < 7; ++k) t3[k] = pfma(splat(c3[ij * 7 + k]), p, t3[k]);
            }
        }
#pragma unroll
        for (int k = 0; k < 5; ++k) y2[k] = pfma(m132, t2[k], y2[k]);
#pragma unroll
        for (int k = 0; k < 7; ++k) y3[k] = pfma(m133, t3[k], y3[k]);
    }

    // group (2,3) -> L=1,2,3 (shared products)
    {
        cgp c1 = CGP(cg231);
        cgp c2 = CGP(cg232);
        cgp c3 = CGP(cg233);
        v2f t1[3] = {}, t2[5] = {}, t3[7] = {};
#pragma unroll
        for (int i = 0; i < 5; ++i) {
#pragma unroll
            for (int j = 0; j < 7; ++j) {
                const int ij = i * 7 + j;
                const v2f p = a2[i] * a3[j];
#pragma unroll
                for (int k = 0; k < 3; ++k) t1[k] = pfma(splat(c1[ij * 3 + k]), p, t1[k]);
#pragma unroll
                for (int k = 0; k < 5; ++k) t2[k] = pfma(splat(c2[ij * 5 + k]), p, t2[k]);
#pragma unroll
                for (int k = 0; k < 7; ++k) t3[k] = pfma(splat(c3[ij * 7 + k]), p, t3[k]);
            }
        }
#pragma unroll
        for (int k = 0; k < 3; ++k) y1[k] = pfma(m231, t1[k], y1[k]);
#pragma unroll
        for (int k = 0; k < 5; ++k) y2[k] = pfma(m232, t2[k], y2[k]);
#pragma unroll
        for (int k = 0; k < 7; ++k) y3[k] = pfma(m233, t3[k], y3[k]);
    }

    // ---- store (concatenated outputs: y0 | y1 | y2 | y3) ----
    float* o0 = out;                          // N*1*F
    float* o1 = out + (size_t)NN * FF;        // N*3*F
    float* o2 = out + (size_t)NN * 4 * FF;    // N*5*F
    float* o3 = out + (size_t)NN * 9 * FF;    // N*7*F

    st2(o0 + n * FF + f2, y0);
#pragma unroll
    for (int k = 0; k < 3; ++k) st2(o1 + (n * 3 + k) * FF + f2, y1[k]);
#pragma unroll
    for (int k = 0; k < 5; ++k) st2(o2 + (n * 5 + k) * FF + f2, y2[k]);
#pragma unroll
    for (int k = 0; k < 7; ++k) st2(o3 + (n * 7 + k) * FF + f2, y3[k]);
}

extern "C" void kernel_launch(void* const* d_in, const int* in_sizes, int n_in,
                              void* d_out, int out_size, void* d_ws, size_t ws_size,
                              hipStream_t stream) {
    const float* x0 = (const float*)d_in[0];
    const float* x1 = (const float*)d_in[1];
    const float* x2 = (const float*)d_in[2];
    const float* x3 = (const float*)d_in[3];
    const float* keep0 = (const float*)d_in[4];
    const float* keep1 = (const float*)d_in[5];
    const float* keep2 = (const float*)d_in[6];
    const float* keep3 = (const float*)d_in[7];
    const float* mix011 = (const float*)d_in[8];
    const float* cg011  = (const float*)d_in[9];
    const float* mix022 = (const float*)d_in[10];
    const float* cg022  = (const float*)d_in[11];
    const float* mix033 = (const float*)d_in[12];
    const float* cg033  = (const float*)d_in[13];
    const float* mix121 = (const float*)d_in[14];
    const float* cg121  = (const float*)d_in[15];
    const float* mix122 = (const float*)d_in[16];
    const float* cg122  = (const float*)d_in[17];
    const float* mix123 = (const float*)d_in[18];
    const float* cg123  = (const float*)d_in[19];
    const float* mix132 = (const float*)d_in[20];
    const float* cg132  = (const float*)d_in[21];
    const float* mix133 = (const float*)d_in[22];
    const float* cg133  = (const float*)d_in[23];
    const float* mix231 = (const float*)d_in[24];
    const float* cg231  = (const float*)d_in[25];
    const float* mix232 = (const float*)d_in[26];
    const float* cg232  = (const float*)d_in[27];
    const float* mix233 = (const float*)d_in[28];
    const float* cg233  = (const float*)d_in[29];

    dim3 grid(NN / NODES_PER_BLOCK);  // 5000
    dim3 block(512);                  // 8 waves = 4 nodes (128 threads each)
    hipLaunchKernelGGL(selfmix_kernel, grid, block, 0, stream,
                       x0, x1, x2, x3,
                       keep0, keep1, keep2, keep3,
                       mix011, cg011, mix022, cg022, mix033, cg033,
                       mix121, cg121, mix122, cg122, mix123, cg123,
                       mix132, cg132, mix133, cg133,
                       mix231, cg231, mix232, cg232, mix233, cg233,
                       (float*)d_out);
}

// Round 8
// 167.480 us; speedup vs baseline: 5.1546x; 1.1584x over previous
//
#include <hip/hip_runtime.h>
#include <stdint.h>

constexpr int NN = 20000;
constexpr int FF = 256;
constexpr int NODES_PER_BLOCK = 2;   // 256 threads = 2 nodes x 128 threads (4 waves)

typedef float v2f __attribute__((ext_vector_type(2)));

// Scalar path for CG coefficients: addrspace(4) (constant) + wave-uniform
// address -> s_load -> SGPR, splat into packed operand.
typedef const __attribute__((address_space(4))) float* cgp;
#define CGP(p) ((cgp)(uintptr_t)(p))

__device__ __forceinline__ v2f ld2(const float* p) {
    return *(const v2f*)p;
}
__device__ __forceinline__ void st2(float* p, v2f v) {
    *(v2f*)p = v;
}
__device__ __forceinline__ v2f pfma(v2f a, v2f b, v2f c) {
    return __builtin_elementwise_fma(a, b, c);
}
__device__ __forceinline__ v2f splat(float s) {
    v2f r = {s, s};
    return r;
}

__global__ __launch_bounds__(256) void selfmix_kernel(
    const float* __restrict__ x0, const float* __restrict__ x1,
    const float* __restrict__ x2, const float* __restrict__ x3,
    const float* __restrict__ keep0, const float* __restrict__ keep1,
    const float* __restrict__ keep2, const float* __restrict__ keep3,
    const float* __restrict__ mix011, const float* __restrict__ cg011,
    const float* __restrict__ mix022, const float* __restrict__ cg022,
    const float* __restrict__ mix033, const float* __restrict__ cg033,
    const float* __restrict__ mix121, const float* __restrict__ cg121,
    const float* __restrict__ mix122, const float* __restrict__ cg122,
    const float* __restrict__ mix123, const float* __restrict__ cg123,
    const float* __restrict__ mix132, const float* __restrict__ cg132,
    const float* __restrict__ mix133, const float* __restrict__ cg133,
    const float* __restrict__ mix231, const float* __restrict__ cg231,
    const float* __restrict__ mix232, const float* __restrict__ cg232,
    const float* __restrict__ mix233, const float* __restrict__ cg233,
    float* __restrict__ out)
{
    const int sub = threadIdx.x >> 7;            // node sub-index in block (0..1)
    const int fp  = threadIdx.x & 127;           // feature-pair index 0..127
    const int n   = blockIdx.x * NODES_PER_BLOCK + sub;
    const int f2  = fp * 2;

    // ---- per-feature coefficients (coalesced float2 loads) ----
    const v2f k0 = ld2(keep0 + f2), k1 = ld2(keep1 + f2);
    const v2f k2 = ld2(keep2 + f2), k3 = ld2(keep3 + f2);
    const v2f m011 = ld2(mix011 + f2), m022 = ld2(mix022 + f2), m033 = ld2(mix033 + f2);
    const v2f m121 = ld2(mix121 + f2), m122 = ld2(mix122 + f2), m123 = ld2(mix123 + f2);
    const v2f m132 = ld2(mix132 + f2), m133 = ld2(mix133 + f2);
    const v2f m231 = ld2(mix231 + f2), m232 = ld2(mix232 + f2), m233 = ld2(mix233 + f2);

    // ---- load x fragments (8 B/lane, fully coalesced) ----
    v2f a0 = ld2(x0 + n * FF + f2);
    v2f a1[3], a2[5], a3[7];
#pragma unroll
    for (int i = 0; i < 3; ++i) a1[i] = ld2(x1 + (n * 3 + i) * FF + f2);
#pragma unroll
    for (int i = 0; i < 5; ++i) a2[i] = ld2(x2 + (n * 5 + i) * FF + f2);
#pragma unroll
    for (int i = 0; i < 7; ++i) a3[i] = ld2(x3 + (n * 7 + i) * FF + f2);

    // ---- keep path ----
    v2f y0 = k0 * a0;
    v2f y1[3], y2[5], y3[7];
#pragma unroll
    for (int i = 0; i < 3; ++i) y1[i] = k1 * a1[i];
#pragma unroll
    for (int i = 0; i < 5; ++i) y2[i] = k2 * a2[i];
#pragma unroll
    for (int i = 0; i < 7; ++i) y3[i] = k3 * a3[i];

    // ---- mixing path: ij-outer, k-inner; packed FMAs, cg via SGPR splat ----

    // group (0,1) -> L=1
    {
        cgp cg = CGP(cg011);
        v2f t[3] = {};
#pragma unroll
        for (int j = 0; j < 3; ++j) {
            const v2f p = a0 * a1[j];
#pragma unroll
            for (int k = 0; k < 3; ++k) t[k] = pfma(splat(cg[j * 3 + k]), p, t[k]);
        }
#pragma unroll
        for (int k = 0; k < 3; ++k) y1[k] = pfma(m011, t[k], y1[k]);
    }

    // group (0,2) -> L=2
    {
        cgp cg = CGP(cg022);
        v2f t[5] = {};
#pragma unroll
        for (int j = 0; j < 5; ++j) {
            const v2f p = a0 * a2[j];
#pragma unroll
            for (int k = 0; k < 5; ++k) t[k] = pfma(splat(cg[j * 5 + k]), p, t[k]);
        }
#pragma unroll
        for (int k = 0; k < 5; ++k) y2[k] = pfma(m022, t[k], y2[k]);
    }

    // group (0,3) -> L=3
    {
        cgp cg = CGP(cg033);
        v2f t[7] = {};
#pragma unroll
        for (int j = 0; j < 7; ++j) {
            const v2f p = a0 * a3[j];
#pragma unroll
            for (int k = 0; k < 7; ++k) t[k] = pfma(splat(cg[j * 7 + k]), p, t[k]);
        }
#pragma unroll
        for (int k = 0; k < 7; ++k) y3[k] = pfma(m033, t[k], y3[k]);
    }

    // group (1,2) -> L=1,2,3 (shared products)
    {
        cgp c1 = CGP(cg121);
        cgp c2 = CGP(cg122);
        cgp c3 = CGP(cg123);
        v2f t1[3] = {}, t2[5] = {}, t3[7] = {};
#pragma unroll
        for (int i = 0; i < 3; ++i) {
#pragma unroll
            for (int j = 0; j < 5; ++j) {
                const int ij = i * 5 + j;
                const v2f p = a1[i] * a2[j];
#pragma unroll
                for (int k = 0; k < 3; ++k) t1[k] = pfma(splat(c1[ij * 3 + k]), p, t1[k]);
#pragma unroll
                for (int k = 0; k < 5; ++k) t2[k] = pfma(splat(c2[ij * 5 + k]), p, t2[k]);
#pragma unroll
                for (int k = 0; k < 7; ++k) t3[k] = pfma(splat(c3[ij * 7 + k]), p, t3[k]);
            }
        }
#pragma unroll
        for (int k = 0; k < 3; ++k) y1[k] = pfma(m121, t1[k], y1[k]);
#pragma unroll
        for (int k = 0; k < 5; ++k) y2[k] = pfma(m122, t2[k], y2[k]);
#pragma unroll
        for (int k = 0; k < 7; ++k) y3[k] = pfma(m123, t3[k], y3[k]);
    }

    // group (1,3) -> L=2,3 (shared products)
    {
        cgp c2 = CGP(cg132);
        cgp c3 = CGP(cg133);
        v2f t2[5] = {}, t3[7] = {};
#pragma unroll
        for (int i = 0; i < 3; ++i) {
#pragma unroll
            for (int j = 0; j < 7; ++j) {
                const int ij = i * 7 + j;
                const v2f p = a1[i] * a3[j];
#pragma unroll
                for (int k = 0; k < 5; ++k) t2[k] = pfma(splat(c2[ij * 5 + k]), p, t2[k]);
#pragma unroll
                for (int k = 0; k < 7; ++k) t3[k] = pfma(splat(c3[ij * 7 + k]), p, t3[k]);
            }
        }
#pragma unroll
        for (int k = 0; k < 5; ++k) y2[k] = pfma(m132, t2[k], y2[k]);
#pragma unroll
        for (int k = 0; k < 7; ++k) y3[k] = pfma(m133, t3[k], y3[k]);
    }

    // group (2,3) -> L=1,2,3 (shared products)
    {
        cgp c1 = CGP(cg231);
        cgp c2 = CGP(cg232);
        cgp c3 = CGP(cg233);
        v2f t1[3] = {}, t2[5] = {}, t3[7] = {};
#pragma unroll
        for (int i = 0; i < 5; ++i) {
#pragma unroll
            for (int j = 0; j < 7; ++j) {
                const int ij = i * 7 + j;
                const v2f p = a2[i] * a3[j];
#pragma unroll
                for (int k = 0; k < 3; ++k) t1[k] = pfma(splat(c1[ij * 3 + k]), p, t1[k]);
#pragma unroll
                for (int k = 0; k < 5; ++k) t2[k] = pfma(splat(c2[ij * 5 + k]), p, t2[k]);
#pragma unroll
                for (int k = 0; k < 7; ++k) t3[k] = pfma(splat(c3[ij * 7 + k]), p, t3[k]);
            }
        }
#pragma unroll
        for (int k = 0; k < 3; ++k) y1[k] = pfma(m231, t1[k], y1[k]);
#pragma unroll
        for (int k = 0; k < 5; ++k) y2[k] = pfma(m232, t2[k], y2[k]);
#pragma unroll
        for (int k = 0; k < 7; ++k) y3[k] = pfma(m233, t3[k], y3[k]);
    }

    // ---- store (concatenated outputs: y0 | y1 | y2 | y3) ----
    float* o0 = out;                          // N*1*F
    float* o1 = out + (size_t)NN * FF;        // N*3*F
    float* o2 = out + (size_t)NN * 4 * FF;    // N*5*F
    float* o3 = out + (size_t)NN * 9 * FF;    // N*7*F

    st2(o0 + n * FF + f2, y0);
#pragma unroll
    for (int k = 0; k < 3; ++k) st2(o1 + (n * 3 + k) * FF + f2, y1[k]);
#pragma unroll
    for (int k = 0; k < 5; ++k) st2(o2 + (n * 5 + k) * FF + f2, y2[k]);
#pragma unroll
    for (int k = 0; k < 7; ++k) st2(o3 + (n * 7 + k) * FF + f2, y3[k]);
}

extern "C" void kernel_launch(void* const* d_in, const int* in_sizes, int n_in,
                              void* d_out, int out_size, void* d_ws, size_t ws_size,
                              hipStream_t stream) {
    const float* x0 = (const float*)d_in[0];
    const float* x1 = (const float*)d_in[1];
    const float* x2 = (const float*)d_in[2];
    const float* x3 = (const float*)d_in[3];
    const float* keep0 = (const float*)d_in[4];
    const float* keep1 = (const float*)d_in[5];
    const float* keep2 = (const float*)d_in[6];
    const float* keep3 = (const float*)d_in[7];
    const float* mix011 = (const float*)d_in[8];
    const float* cg011  = (const float*)d_in[9];
    const float* mix022 = (const float*)d_in[10];
    const float* cg022  = (const float*)d_in[11];
    const float* mix033 = (const float*)d_in[12];
    const float* cg033  = (const float*)d_in[13];
    const float* mix121 = (const float*)d_in[14];
    const float* cg121  = (const float*)d_in[15];
    const float* mix122 = (const float*)d_in[16];
    const float* cg122  = (const float*)d_in[17];
    const float* mix123 = (const float*)d_in[18];
    const float* cg123  = (const float*)d_in[19];
    const float* mix132 = (const float*)d_in[20];
    const float* cg132  = (const float*)d_in[21];
    const float* mix133 = (const float*)d_in[22];
    const float* cg133  = (const float*)d_in[23];
    const float* mix231 = (const float*)d_in[24];
    const float* cg231  = (const float*)d_in[25];
    const float* mix232 = (const float*)d_in[26];
    const float* cg232  = (const float*)d_in[27];
    const float* mix233 = (const float*)d_in[28];
    const float* cg233  = (const float*)d_in[29];

    dim3 grid(NN / NODES_PER_BLOCK);  // 10000
    dim3 block(256);                  // 4 waves = 2 nodes (128 threads each)
    hipLaunchKernelGGL(selfmix_kernel, grid, block, 0, stream,
                       x0, x1, x2, x3,
                       keep0, keep1, keep2, keep3,
                       mix011, cg011, mix022, cg022, mix033, cg033,
                       mix121, cg121, mix122, cg122, mix123, cg123,
                       mix132, cg132, mix133, cg133,
                       mix231, cg231, mix232, cg232, mix233, cg233,
                       (float*)d_out);
}